// Round 5
// baseline (176.959 us; speedup 1.0000x reference)
//
#include <hip/hip_runtime.h>
#include <stdint.h>

typedef unsigned short u16;
typedef unsigned int u32;
typedef __attribute__((ext_vector_type(8))) short short8;
typedef __attribute__((ext_vector_type(4))) float floatx4;

__device__ __forceinline__ u16 f2b(float f) {
    u32 u = __builtin_bit_cast(u32, f);
    return (u16)((u + 0x7fffu + ((u >> 16) & 1u)) >> 16);
}
__device__ __forceinline__ float b2f(u16 b) {
    u32 u = ((u32)b) << 16;
    return __builtin_bit_cast(float, u);
}
__device__ __forceinline__ void gld16(const void* g, void* l) {
    __builtin_amdgcn_global_load_lds(
        (const __attribute__((address_space(1))) u32*)g,
        (__attribute__((address_space(3))) u32*)l, 16, 0, 0);
}

// ---- prep_all: blocks [0,8192): row norms + xb=bf16(x); blocks [8192,8448): W^T ----
__global__ __launch_bounds__(256) void prep_all(
    const float* __restrict__ x, const float* __restrict__ wgt,
    float* __restrict__ rnorm, float* __restrict__ srnorm,
    u16* __restrict__ xb, u16* __restrict__ Wt) {
    __shared__ float tile[64][65];
    int bid = blockIdx.x;
    int t = threadIdx.x;
    if (bid < 8192) {
        float4 v = ((const float4*)(x + (long)bid * 1024))[t];
        float ss = v.x * v.x + v.y * v.y + v.z * v.z + v.w * v.w;
        #pragma unroll
        for (int off = 32; off > 0; off >>= 1) ss += __shfl_down(ss, off);
        if ((t & 63) == 0) tile[0][t >> 6] = ss;
        __syncthreads();
        if (t == 0) {
            float r = 1.0f / fmaxf(sqrtf(tile[0][0] + tile[0][1] + tile[0][2] + tile[0][3]), 1e-12f);
            rnorm[bid] = r;
            srnorm[bid] = sqrtf(r);
        }
        ushort4 o;
        o.x = f2b(v.x); o.y = f2b(v.y); o.z = f2b(v.z); o.w = f2b(v.w);
        *(ushort4*)(xb + (long)bid * 1024 + t * 4) = o;
    } else {
        int b2 = bid - 8192;
        int r0 = (b2 >> 4) * 64, c0 = (b2 & 15) * 64;
        #pragma unroll
        for (int i = 0; i < 4; i++) {
            int lin = i * 256 + t;
            int rr = lin >> 4, c4 = (lin & 15) << 2;
            float4 v = *(const float4*)(wgt + (long)(r0 + rr) * 1024 + c0 + c4);
            tile[rr][c4] = v.x; tile[rr][c4 + 1] = v.y; tile[rr][c4 + 2] = v.z; tile[rr][c4 + 3] = v.w;
        }
        __syncthreads();
        #pragma unroll
        for (int i = 0; i < 4; i++) {
            int lin = i * 256 + t;
            int cc = lin >> 4, r4 = (lin & 15) << 2;
            ushort4 o;
            o.x = f2b(tile[r4][cc]);     o.y = f2b(tile[r4 + 1][cc]);
            o.z = f2b(tile[r4 + 2][cc]); o.w = f2b(tile[r4 + 3][cc]);
            *(ushort4*)(Wt + (long)(c0 + cc) * 1024 + r0 + r4) = o;
        }
    }
}

// ---- transpose_xb: YT[c][r] = bf16(xb[r][c] * sr[r]), src bf16 [8192][1024] ----
__global__ __launch_bounds__(256) void transpose_xb(
    const u16* __restrict__ xb, const float* __restrict__ sr, u16* __restrict__ YT) {
    __shared__ u16 tile[64][72];
    __shared__ float rb[64];
    int r0 = blockIdx.x * 64, c0 = blockIdx.y * 64;
    int t = threadIdx.x;
    if (t < 64) rb[t] = sr[r0 + t];
    __syncthreads();
    #pragma unroll
    for (int i = 0; i < 4; i++) {
        int lin = i * 256 + t;
        int rr = lin >> 4, c4 = (lin & 15) << 2;
        ushort4 v = *(const ushort4*)(xb + (long)(r0 + rr) * 1024 + c0 + c4);
        float s = rb[rr];
        tile[rr][c4]     = f2b(b2f(v.x) * s);
        tile[rr][c4 + 1] = f2b(b2f(v.y) * s);
        tile[rr][c4 + 2] = f2b(b2f(v.z) * s);
        tile[rr][c4 + 3] = f2b(b2f(v.w) * s);
    }
    __syncthreads();
    #pragma unroll
    for (int i = 0; i < 4; i++) {
        int lin = i * 256 + t;
        int cc = lin >> 4, r4 = (lin & 15) << 2;
        ushort4 o;
        o.x = tile[r4][cc]; o.y = tile[r4 + 1][cc];
        o.z = tile[r4 + 2][cc]; o.w = tile[r4 + 3][cc];
        *(ushort4*)(YT + (long)(c0 + cc) * 8192 + r0 + r4) = o;
    }
}

// ---- symmetric reduce for G: sums S bf16 slabs; kept 64-tiles (ti<=2*(tj>>1)+1)
// direct; others mirrored via LDS transpose. D = Gb bf16 [1024][1024]. ----
__global__ __launch_bounds__(256) void reduce_sym64_b16(
    const u16* __restrict__ P, u16* __restrict__ D, int S, long E) {
    __shared__ float lt[64][65];
    int ti = blockIdx.x >> 4, tj = blockIdx.x & 15;
    int t = threadIdx.x;
    int r = t >> 4, c4 = (t & 15) << 2;
    int kept = (ti <= 2 * (tj >> 1) + 1);
    if (kept) {
        #pragma unroll
        for (int it = 0; it < 4; it++) {
            int row = 64 * ti + it * 16 + r;
            long idx = (long)row * 1024 + 64 * tj + c4;
            float s0 = 0, s1 = 0, s2 = 0, s3 = 0;
            for (int z = 0; z < S; z++) {
                ushort4 v = *(const ushort4*)(P + (long)z * E + idx);
                s0 += b2f(v.x); s1 += b2f(v.y); s2 += b2f(v.z); s3 += b2f(v.w);
            }
            ushort4 o; o.x = f2b(s0); o.y = f2b(s1); o.z = f2b(s2); o.w = f2b(s3);
            *(ushort4*)(D + idx) = o;
        }
    } else {
        #pragma unroll
        for (int it = 0; it < 4; it++) {
            int row = it * 16 + r;
            long idx = (long)(64 * tj + row) * 1024 + 64 * ti + c4;
            float s0 = 0, s1 = 0, s2 = 0, s3 = 0;
            for (int z = 0; z < S; z++) {
                ushort4 v = *(const ushort4*)(P + (long)z * E + idx);
                s0 += b2f(v.x); s1 += b2f(v.y); s2 += b2f(v.z); s3 += b2f(v.w);
            }
            lt[row][c4] = s0; lt[row][c4 + 1] = s1; lt[row][c4 + 2] = s2; lt[row][c4 + 3] = s3;
        }
        __syncthreads();
        #pragma unroll
        for (int it = 0; it < 4; it++) {
            int dr = it * 16 + r;
            ushort4 o;
            o.x = f2b(lt[c4 + 0][dr]); o.y = f2b(lt[c4 + 1][dr]);
            o.z = f2b(lt[c4 + 2][dr]); o.w = f2b(lt[c4 + 3][dr]);
            *(ushort4*)(D + (long)(64 * ti + dr) * 1024 + 64 * tj + c4) = o;
        }
    }
}

// ---- reduce S bf16 slabs of E elements -> bf16 ----
__global__ __launch_bounds__(256) void reduce_cast_b16(
    const u16* __restrict__ P, u16* __restrict__ D, int S, long E) {
    long i = ((long)blockIdx.x * 256 + threadIdx.x) * 4;
    float s0 = 0, s1 = 0, s2 = 0, s3 = 0;
    for (int z = 0; z < S; z++) {
        ushort4 v = *(const ushort4*)(P + (long)z * E + i);
        s0 += b2f(v.x); s1 += b2f(v.y); s2 += b2f(v.z); s3 += b2f(v.w);
    }
    ushort4 o; o.x = f2b(s0); o.y = f2b(s1); o.z = f2b(s2); o.w = f2b(s3);
    *(ushort4*)(D + i) = o;
}

// ---- GEMM: tile 64(M)x128(N), BK=64, 256 thr, 4 waves as 2x2 of 32x64.
// XOR-swizzled LDS, conflict-free b128 reads. A:[M][K] rm bf16, B:[N][K] rm bf16.
// Cp!=null: bf16 partial store at slab offset z*coffz. Else fp32 C with rowscale.
// sym=1: grid.x=72 tiles (tm<=2*tn+1) of a 16x8 tile grid. ----
__global__ __launch_bounds__(256, 4) void gemm64x128(
    const u16* __restrict__ A, const u16* __restrict__ B,
    float* __restrict__ C, u16* __restrict__ Cp, const float* __restrict__ rowscale,
    int lda, int ldb, int ldc, int tilesN, int kIters, long coffz, int sym) {
    __shared__ __align__(16) u16 As[64 * 64];
    __shared__ __align__(16) u16 Bs[128 * 64];
    int tm, tn;
    if (sym) {
        int id = blockIdx.x, j = 0;
        while (true) {
            int c = (2 * j + 2 < 16) ? (2 * j + 2) : 16;
            if (id < c) break;
            id -= c; j++;
        }
        tn = j; tm = id;
    } else {
        tm = blockIdx.x / tilesN; tn = blockIdx.x % tilesN;
    }
    long kOff = (long)blockIdx.y * kIters * 64;
    const u16* Ap = A + (long)tm * 64 * lda + kOff;
    const u16* Bp = B + (long)tn * 128 * ldb + kOff;
    long coff = (long)blockIdx.y * coffz;

    int t = threadIdx.x;
    int lane = t & 63, w = t >> 6;
    int wm = (w & 1) * 32, wn = (w >> 1) * 64;
    int r16 = lane & 15, q = lane >> 4;

    int acl[2], bcl[4];
    #pragma unroll
    for (int j = 0; j < 2; j++) acl[j] = (w * 2 + j) * 64 + lane;
    #pragma unroll
    for (int j = 0; j < 4; j++) bcl[j] = (w * 4 + j) * 64 + lane;

    floatx4 acc[2][4];
    #pragma unroll
    for (int i = 0; i < 2; i++)
        #pragma unroll
        for (int j = 0; j < 4; j++) acc[i][j] = (floatx4){0.f, 0.f, 0.f, 0.f};

    for (int kt = 0; kt < kIters; kt++) {
        long kk = (long)kt * 64;
        #pragma unroll
        for (int j = 0; j < 2; j++) {
            int cl = acl[j], row = cl >> 3, cg = (cl & 7) ^ (row & 7);
            gld16(Ap + (long)row * lda + kk + cg * 8, (void*)&As[cl * 8]);
        }
        #pragma unroll
        for (int j = 0; j < 4; j++) {
            int cl = bcl[j], row = cl >> 3, cg = (cl & 7) ^ (row & 7);
            gld16(Bp + (long)row * ldb + kk + cg * 8, (void*)&Bs[cl * 8]);
        }
        __syncthreads();
        #pragma unroll
        for (int ks = 0; ks < 2; ks++) {
            short8 a[2], b[4];
            #pragma unroll
            for (int i = 0; i < 2; i++) {
                int rr = wm + i * 16 + r16;
                int cc = (ks * 4 + q) ^ (rr & 7);
                a[i] = *(const short8*)&As[rr * 64 + cc * 8];
            }
            #pragma unroll
            for (int j = 0; j < 4; j++) {
                int rr = wn + j * 16 + r16;
                int cc = (ks * 4 + q) ^ (rr & 7);
                b[j] = *(const short8*)&Bs[rr * 64 + cc * 8];
            }
            #pragma unroll
            for (int i = 0; i < 2; i++)
                #pragma unroll
                for (int j = 0; j < 4; j++)
                    acc[i][j] = __builtin_amdgcn_mfma_f32_16x16x32_bf16(a[i], b[j], acc[i][j], 0, 0, 0);
        }
        __syncthreads();
    }

    int m0 = tm * 64 + wm, n0 = tn * 128 + wn;
    #pragma unroll
    for (int i = 0; i < 2; i++) {
        int mm = m0 + i * 16 + q * 4;
        float rs[4];
        #pragma unroll
        for (int r = 0; r < 4; r++) rs[r] = (rowscale != nullptr) ? rowscale[mm + r] : 1.0f;
        #pragma unroll
        for (int j = 0; j < 4; j++) {
            int nn = n0 + j * 16 + r16;
            #pragma unroll
            for (int r = 0; r < 4; r++) {
                long idx = (long)(mm + r) * ldc + nn;
                if (Cp != nullptr) Cp[coff + idx] = f2b(acc[i][j][r]);
                else               C[idx] = acc[i][j][r] * rs[r];
            }
        }
    }
}

extern "C" void kernel_launch(void* const* d_in, const int* in_sizes, int n_in,
                              void* d_out, int out_size, void* d_ws, size_t ws_size,
                              hipStream_t stream) {
    const float* x = (const float*)d_in[0];
    const float* wgt = (const float*)d_in[1];
    float* out = (float*)d_out;
    char* ws = (char*)d_ws;

    const size_t MB = 1048576;
    float* rnorm  = (float*)ws;                       // 32 KB
    float* srnorm = (float*)(ws + 32768);             // 32 KB
    u16*   xb     = (u16*)(ws + 65536);               // 16 MB  bf16(x) [8192][1024]
    u16*   YT     = (u16*)(ws + 65536 + 16 * MB);     // 16 MB  Y^T bf16 [1024][8192]
    u16*   Wt     = (u16*)(ws + 65536 + 32 * MB);     //  2 MB  W^T bf16
    u16*   Gb     = (u16*)(ws + 65536 + 34 * MB);     //  2 MB  G bf16
    u16*   Mt     = (u16*)(ws + 65536 + 36 * MB);     //  2 MB  M^T bf16
    u16*   Gp     = (u16*)(ws + 65536 + 38 * MB);     // 32 MB  16 bf16 G-partial slabs
    u16*   Mp     = (u16*)(ws + 65536 + 70 * MB);     //  8 MB   4 bf16 M-partial slabs
    // total ~78 MB

    // 1) norms + xb (blocks 0..8191) and W^T (blocks 8192..8447), one launch
    prep_all<<<8448, 256, 0, stream>>>(x, wgt, rnorm, srnorm, xb, Wt);
    // 2) YT = (diag(sqrt r)·x)^T from xb
    transpose_xb<<<dim3(128, 16), 256, 0, stream>>>(xb, srnorm, YT);
    // 3) G = Y^T·Y, sym tiles (72), split-K=16 -> bf16 partials (1152 blocks, 4.5/CU)
    gemm64x128<<<dim3(72, 16), 256, 0, stream>>>(YT, YT, nullptr, Gp, nullptr,
                                                 8192, 8192, 1024, 8, 8, 1048576, 1);
    // 4) Gb = bf16(sum Gp) with lower-triangle mirror
    reduce_sym64_b16<<<256, 256, 0, stream>>>(Gp, Gb, 16, 1048576);
    // 5) M^T = W^T·G, split-K=4 -> bf16 partials (512 blocks, 2/CU)
    gemm64x128<<<dim3(128, 4), 256, 0, stream>>>(Wt, Gb, nullptr, Mp, nullptr,
                                                 1024, 1024, 1024, 8, 4, 1048576, 0);
    // 6) Mt = bf16(sum Mp)
    reduce_cast_b16<<<1024, 256, 0, stream>>>(Mp, Mt, 4, 1048576);
    // 7) out = diag(rnorm)·xb·M  (1024 blocks, 4/CU)
    gemm64x128<<<dim3(1024, 1), 256, 0, stream>>>(xb, Mt, out, nullptr, rnorm,
                                                  1024, 1024, 1024, 8, 16, 0, 0);
}

// Round 6
// 169.614 us; speedup vs baseline: 1.0433x; 1.0433x over previous
//
#include <hip/hip_runtime.h>
#include <stdint.h>

typedef unsigned short u16;
typedef unsigned int u32;
typedef __attribute__((ext_vector_type(8))) short short8;
typedef __attribute__((ext_vector_type(4))) float floatx4;

__device__ __forceinline__ u16 f2b(float f) {
    u32 u = __builtin_bit_cast(u32, f);
    return (u16)((u + 0x7fffu + ((u >> 16) & 1u)) >> 16);
}
__device__ __forceinline__ float b2f(u16 b) {
    u32 u = ((u32)b) << 16;
    return __builtin_bit_cast(float, u);
}
__device__ __forceinline__ void gld16(const void* g, void* l) {
    __builtin_amdgcn_global_load_lds(
        (const __attribute__((address_space(1))) u32*)g,
        (__attribute__((address_space(3))) u32*)l, 16, 0, 0);
}

// ---- row 2-norm recips: rnorm = 1/max(||row||,eps), srnorm = sqrt(rnorm) ----
__global__ __launch_bounds__(256) void prep_norms(
    const float* __restrict__ x, float* __restrict__ rnorm, float* __restrict__ srnorm) {
    int row = blockIdx.x;
    int t = threadIdx.x;
    float4 v = ((const float4*)(x + (long)row * 1024))[t];
    float ss = v.x * v.x + v.y * v.y + v.z * v.z + v.w * v.w;
    #pragma unroll
    for (int off = 32; off > 0; off >>= 1) ss += __shfl_down(ss, off);
    __shared__ float red[4];
    if ((t & 63) == 0) red[t >> 6] = ss;
    __syncthreads();
    if (t == 0) {
        float r = 1.0f / fmaxf(sqrtf(red[0] + red[1] + red[2] + red[3]), 1e-12f);
        rnorm[row] = r;
        srnorm[row] = sqrtf(r);
    }
}

// ---- dual-output scale+cast: dstT[c][r] = dstR[r][c] = bf16(src[r][c]*sr[r]) ----
__global__ __launch_bounds__(256) void transpose_scale_dual(
    const float* __restrict__ src, const float* __restrict__ sr,
    u16* __restrict__ dstT, u16* __restrict__ dstR, int rows, int cols) {
    __shared__ float tile[64][65];
    __shared__ float rbuf[64];
    int r0 = blockIdx.x * 64, c0 = blockIdx.y * 64;
    int t = threadIdx.x;
    if (t < 64) rbuf[t] = (sr != nullptr) ? sr[r0 + t] : 1.0f;
    __syncthreads();
    #pragma unroll
    for (int i = 0; i < 4; i++) {
        int lin = i * 256 + t;
        int rr = lin >> 4, c4 = (lin & 15) << 2;
        float4 v = *(const float4*)(src + (long)(r0 + rr) * cols + c0 + c4);
        float s = rbuf[rr];
        v.x *= s; v.y *= s; v.z *= s; v.w *= s;
        tile[rr][c4] = v.x; tile[rr][c4 + 1] = v.y; tile[rr][c4 + 2] = v.z; tile[rr][c4 + 3] = v.w;
        if (dstR != nullptr) {
            ushort4 o; o.x = f2b(v.x); o.y = f2b(v.y); o.z = f2b(v.z); o.w = f2b(v.w);
            *(ushort4*)(dstR + (long)(r0 + rr) * cols + c0 + c4) = o;
        }
    }
    __syncthreads();
    #pragma unroll
    for (int i = 0; i < 4; i++) {
        int lin = i * 256 + t;
        int cc = lin >> 4, r4 = (lin & 15) << 2;
        ushort4 o;
        o.x = f2b(tile[r4][cc]);
        o.y = f2b(tile[r4 + 1][cc]);
        o.z = f2b(tile[r4 + 2][cc]);
        o.w = f2b(tile[r4 + 3][cc]);
        *(ushort4*)(dstT + (long)(c0 + cc) * rows + r0 + r4) = o;
    }
}

// ---- symmetric reduce for G: sum S bf16 slabs; kept 64-tiles (ti<=2*(tj>>1)+1)
// direct; others mirrored via LDS transpose. ----
__global__ __launch_bounds__(256) void reduce_sym64_b16(
    const u16* __restrict__ P, u16* __restrict__ D, int S, long E) {
    __shared__ float lt[64][65];
    int ti = blockIdx.x >> 4, tj = blockIdx.x & 15;
    int t = threadIdx.x;
    int r = t >> 4, c4 = (t & 15) << 2;
    int kept = (ti <= 2 * (tj >> 1) + 1);
    if (kept) {
        #pragma unroll
        for (int it = 0; it < 4; it++) {
            int row = 64 * ti + it * 16 + r;
            long idx = (long)row * 1024 + 64 * tj + c4;
            float s0 = 0, s1 = 0, s2 = 0, s3 = 0;
            for (int z = 0; z < S; z++) {
                ushort4 v = *(const ushort4*)(P + (long)z * E + idx);
                s0 += b2f(v.x); s1 += b2f(v.y); s2 += b2f(v.z); s3 += b2f(v.w);
            }
            ushort4 o; o.x = f2b(s0); o.y = f2b(s1); o.z = f2b(s2); o.w = f2b(s3);
            *(ushort4*)(D + idx) = o;
        }
    } else {
        #pragma unroll
        for (int it = 0; it < 4; it++) {
            int row = it * 16 + r;
            long idx = (long)(64 * tj + row) * 1024 + 64 * ti + c4;
            float s0 = 0, s1 = 0, s2 = 0, s3 = 0;
            for (int z = 0; z < S; z++) {
                ushort4 v = *(const ushort4*)(P + (long)z * E + idx);
                s0 += b2f(v.x); s1 += b2f(v.y); s2 += b2f(v.z); s3 += b2f(v.w);
            }
            lt[row][c4] = s0; lt[row][c4 + 1] = s1; lt[row][c4 + 2] = s2; lt[row][c4 + 3] = s3;
        }
        __syncthreads();
        #pragma unroll
        for (int it = 0; it < 4; it++) {
            int dr = it * 16 + r;
            ushort4 o;
            o.x = f2b(lt[c4 + 0][dr]); o.y = f2b(lt[c4 + 1][dr]);
            o.z = f2b(lt[c4 + 2][dr]); o.w = f2b(lt[c4 + 3][dr]);
            *(ushort4*)(D + (long)(64 * ti + dr) * 1024 + 64 * tj + c4) = o;
        }
    }
}

// ---- reduce S bf16 slabs of E elements -> bf16 ----
__global__ __launch_bounds__(256) void reduce_cast_b16(
    const u16* __restrict__ P, u16* __restrict__ D, int S, long E) {
    long i = ((long)blockIdx.x * 256 + threadIdx.x) * 4;
    float s0 = 0, s1 = 0, s2 = 0, s3 = 0;
    for (int z = 0; z < S; z++) {
        ushort4 v = *(const ushort4*)(P + (long)z * E + i);
        s0 += b2f(v.x); s1 += b2f(v.y); s2 += b2f(v.z); s3 += b2f(v.w);
    }
    ushort4 o; o.x = f2b(s0); o.y = f2b(s1); o.z = f2b(s2); o.w = f2b(s3);
    *(ushort4*)(D + i) = o;
}

// ---- GEMM: tile 64(M)x128(N), BK=64, 256 thr, 4 waves as 2x2 of 32x64.
// XOR-swizzled LDS, conflict-free b128 reads. A:[M][K] rm bf16, B:[N][K] rm bf16.
// Cp!=null: bf16 partial store at slab offset z*coffz. Else fp32 C with rowscale.
// sym=1: grid.x=72 tiles (tm<=2*tn+1) of a 16x8 tile grid. ----
__global__ __launch_bounds__(256, 4) void gemm64x128(
    const u16* __restrict__ A, const u16* __restrict__ B,
    float* __restrict__ C, u16* __restrict__ Cp, const float* __restrict__ rowscale,
    int lda, int ldb, int ldc, int tilesN, int kIters, long coffz, int sym) {
    __shared__ __align__(16) u16 As[64 * 64];
    __shared__ __align__(16) u16 Bs[128 * 64];
    int tm, tn;
    if (sym) {
        int id = blockIdx.x, j = 0;
        while (true) {
            int c = (2 * j + 2 < 16) ? (2 * j + 2) : 16;
            if (id < c) break;
            id -= c; j++;
        }
        tn = j; tm = id;
    } else {
        tm = blockIdx.x / tilesN; tn = blockIdx.x % tilesN;
    }
    long kOff = (long)blockIdx.y * kIters * 64;
    const u16* Ap = A + (long)tm * 64 * lda + kOff;
    const u16* Bp = B + (long)tn * 128 * ldb + kOff;
    long coff = (long)blockIdx.y * coffz;

    int t = threadIdx.x;
    int lane = t & 63, w = t >> 6;
    int wm = (w & 1) * 32, wn = (w >> 1) * 64;
    int r16 = lane & 15, q = lane >> 4;

    int acl[2], bcl[4];
    #pragma unroll
    for (int j = 0; j < 2; j++) acl[j] = (w * 2 + j) * 64 + lane;
    #pragma unroll
    for (int j = 0; j < 4; j++) bcl[j] = (w * 4 + j) * 64 + lane;

    floatx4 acc[2][4];
    #pragma unroll
    for (int i = 0; i < 2; i++)
        #pragma unroll
        for (int j = 0; j < 4; j++) acc[i][j] = (floatx4){0.f, 0.f, 0.f, 0.f};

    for (int kt = 0; kt < kIters; kt++) {
        long kk = (long)kt * 64;
        #pragma unroll
        for (int j = 0; j < 2; j++) {
            int cl = acl[j], row = cl >> 3, cg = (cl & 7) ^ (row & 7);
            gld16(Ap + (long)row * lda + kk + cg * 8, (void*)&As[cl * 8]);
        }
        #pragma unroll
        for (int j = 0; j < 4; j++) {
            int cl = bcl[j], row = cl >> 3, cg = (cl & 7) ^ (row & 7);
            gld16(Bp + (long)row * ldb + kk + cg * 8, (void*)&Bs[cl * 8]);
        }
        __syncthreads();
        #pragma unroll
        for (int ks = 0; ks < 2; ks++) {
            short8 a[2], b[4];
            #pragma unroll
            for (int i = 0; i < 2; i++) {
                int rr = wm + i * 16 + r16;
                int cc = (ks * 4 + q) ^ (rr & 7);
                a[i] = *(const short8*)&As[rr * 64 + cc * 8];
            }
            #pragma unroll
            for (int j = 0; j < 4; j++) {
                int rr = wn + j * 16 + r16;
                int cc = (ks * 4 + q) ^ (rr & 7);
                b[j] = *(const short8*)&Bs[rr * 64 + cc * 8];
            }
            #pragma unroll
            for (int i = 0; i < 2; i++)
                #pragma unroll
                for (int j = 0; j < 4; j++)
                    acc[i][j] = __builtin_amdgcn_mfma_f32_16x16x32_bf16(a[i], b[j], acc[i][j], 0, 0, 0);
        }
        __syncthreads();
    }

    int m0 = tm * 64 + wm, n0 = tn * 128 + wn;
    #pragma unroll
    for (int i = 0; i < 2; i++) {
        int mm = m0 + i * 16 + q * 4;
        float rs[4];
        #pragma unroll
        for (int r = 0; r < 4; r++) rs[r] = (rowscale != nullptr) ? rowscale[mm + r] : 1.0f;
        #pragma unroll
        for (int j = 0; j < 4; j++) {
            int nn = n0 + j * 16 + r16;
            #pragma unroll
            for (int r = 0; r < 4; r++) {
                long idx = (long)(mm + r) * ldc + nn;
                if (Cp != nullptr) Cp[coff + idx] = f2b(acc[i][j][r]);
                else               C[idx] = acc[i][j][r] * rs[r];
            }
        }
    }
}

extern "C" void kernel_launch(void* const* d_in, const int* in_sizes, int n_in,
                              void* d_out, int out_size, void* d_ws, size_t ws_size,
                              hipStream_t stream) {
    const float* x = (const float*)d_in[0];
    const float* wgt = (const float*)d_in[1];
    float* out = (float*)d_out;
    char* ws = (char*)d_ws;

    const size_t MB = 1048576;
    float* rnorm  = (float*)ws;                       // 32 KB
    float* srnorm = (float*)(ws + 32768);             // 32 KB
    u16*   YT     = (u16*)(ws + 65536);               // 16 MB  Y^T = (diag(sqrt r)x)^T [1024][8192]
    u16*   Yb     = (u16*)(ws + 65536 + 16 * MB);     // 16 MB  Y row-major [8192][1024]
    u16*   Wt     = (u16*)(ws + 65536 + 32 * MB);     //  2 MB  W^T bf16
    u16*   Gb     = (u16*)(ws + 65536 + 34 * MB);     //  2 MB  G bf16
    u16*   Mt     = (u16*)(ws + 65536 + 36 * MB);     //  2 MB  M^T bf16
    u16*   Gp     = (u16*)(ws + 65536 + 38 * MB);     // 16 MB  8 bf16 G-partial slabs
    u16*   Mp     = (u16*)(ws + 65536 + 54 * MB);     //  8 MB  4 bf16 M-partial slabs
    // total ~62 MB

    // 1) row norms
    prep_norms<<<8192, 256, 0, stream>>>(x, rnorm, srnorm);
    // 2) Y in both layouts from one read of x
    transpose_scale_dual<<<dim3(128, 16), 256, 0, stream>>>(x, srnorm, YT, Yb, 8192, 1024);
    // 3) Wt = W^T bf16
    transpose_scale_dual<<<dim3(16, 16), 256, 0, stream>>>(wgt, nullptr, Wt, nullptr, 1024, 1024);
    // 4) G = Y^T·Y, sym tiles (72), split-K=8, K-chunk 1024 -> bf16 partials (576 blocks)
    gemm64x128<<<dim3(72, 8), 256, 0, stream>>>(YT, YT, nullptr, Gp, nullptr,
                                                8192, 8192, 1024, 8, 16, 1048576, 1);
    // 5) Gb = bf16(sum Gp) with lower-triangle mirror
    reduce_sym64_b16<<<256, 256, 0, stream>>>(Gp, Gb, 8, 1048576);
    // 6) M^T = W^T·G, split-K=4, K-chunk 256 -> bf16 partials (512 blocks, 2/CU)
    gemm64x128<<<dim3(128, 4), 256, 0, stream>>>(Wt, Gb, nullptr, Mp, nullptr,
                                                 1024, 1024, 1024, 8, 4, 1048576, 0);
    // 7) Mt = bf16(sum Mp)
    reduce_cast_b16<<<1024, 256, 0, stream>>>(Mp, Mt, 4, 1048576);
    // 8) out = diag(sqrt r)·Y·M  (1024 blocks, 4/CU)
    gemm64x128<<<dim3(1024, 1), 256, 0, stream>>>(Yb, Mt, out, nullptr, srnorm,
                                                  1024, 1024, 1024, 8, 16, 0, 0);
}